// Round 3
// baseline (116.354 us; speedup 1.0000x reference)
//
#include <hip/hip_runtime.h>

// Problem constants: B=4096 rows, C=4096 channels, M*S=4096 assignment slots.
// Algebraic collapse of the reference:
//   out[b,c] = count[b] * x[b,c],  count[b] = #{(m,s): assignments[m,s]==b}
//   (padding -1 never matches a row index >= 0)
//
// Evidence so far (rounds 0-2):
//   - split count/stream into 2 dispatches: +3 us (launch overhead, stream no
//     faster) -> count phase is FULLY HIDDEN under the HBM stream.
//   - 2 rows/block amortization: neutral. Scan/reduce/barriers are not on the
//     critical path.
// => The kernel is a pure 128 MiB read+write stream at ~82% of copy BW.
// This version: round-0 structure (best measured, 110.08 us) + NONTEMPORAL
// hints on the x loads / out stores only. The streamed 128 MiB is touched
// exactly once; nt keeps it from churning L2, while the 16 KB assignments
// array (re-read by all 4096 blocks) stays on the cached path.

typedef float f32x4 __attribute__((ext_vector_type(4)));

#define BLOCK 256
#define C_VEC 1024            // 4096 floats / 4 per float4
#define VPT 4                 // float4 per thread (1024 / 256)
#define APT 4                 // int4 per thread (1024 / 256)
#define NROWS 4096

__global__ __launch_bounds__(BLOCK) void mux_fused_nt(
    const f32x4* __restrict__ x,
    const int4* __restrict__ a4,
    f32x4* __restrict__ out) {
    const int b = blockIdx.x;
    const int tid = threadIdx.x;

    // 1) issue the row loads early (nontemporal: streamed once, don't cache)
    const long base = (long)b * C_VEC + tid;
    f32x4 v[VPT];
#pragma unroll
    for (int k = 0; k < VPT; ++k)
        v[k] = __builtin_nontemporal_load(&x[base + BLOCK * k]);

    // 2) per-thread match count over assignments (cached path: L2/L3 resident)
    int local = 0;
#pragma unroll
    for (int k = 0; k < APT; ++k) {
        const int4 a = a4[tid + BLOCK * k];
        local += (a.x == b) + (a.y == b) + (a.z == b) + (a.w == b);
    }

    // 3) wave shuffle-reduce (width 64) then cross-wave LDS reduce
#pragma unroll
    for (int off = 32; off > 0; off >>= 1)
        local += __shfl_down(local, off, 64);

    __shared__ int wave_sum[BLOCK / 64];
    __shared__ float s_scale;
    const int wave = tid >> 6;
    if ((tid & 63) == 0) wave_sum[wave] = local;
    __syncthreads();
    if (tid == 0)
        s_scale = (float)(wave_sum[0] + wave_sum[1] + wave_sum[2] + wave_sum[3]);
    __syncthreads();
    const float s = s_scale;

    // 4) scale + nontemporal store
#pragma unroll
    for (int k = 0; k < VPT; ++k) {
        f32x4 w = v[k] * s;
        __builtin_nontemporal_store(w, &out[base + BLOCK * k]);
    }
}

extern "C" void kernel_launch(void* const* d_in, const int* in_sizes, int n_in,
                              void* d_out, int out_size, void* d_ws, size_t ws_size,
                              hipStream_t stream) {
    const float* x = (const float*)d_in[0];
    const int* assignments = (const int*)d_in[1];
    float* out = (float*)d_out;

    mux_fused_nt<<<dim3(NROWS), dim3(BLOCK), 0, stream>>>(
        (const f32x4*)x, (const int4*)assignments, (f32x4*)out);
}

// Round 4
// 110.599 us; speedup vs baseline: 1.0520x; 1.0520x over previous
//
#include <hip/hip_runtime.h>

// Problem constants (from reference setup_inputs):
//   B=4096 (objects/rows), C=4096 (channels), M=64, S=64 -> M*S = 4096 slots.
// Algebraic collapse of the reference:
//   out[b,c] = count[b] * x[b,c], where
//   count[b] = #{(m,s) : assignments[m,s] == b}   (b >= 0, so -1 padding never matches)
//
// ROOFLINE CONFIGURATION (session evidence, rounds 0-3):
//   - Compulsory HBM traffic: 64 MiB x read + 64 MiB out write = 128 MiB
//     -> 21.3 us floor at the 6.29 TB/s measured copy ceiling. Kernel runs
//     ~24-26 us (inferred; below the 41 us harness fills in every profile).
//   - R1 proved the count scan/reduce/barriers are FULLY HIDDEN under the
//     stream: a pure load-mul-store kernel with the count split out was NOT
//     faster (and the extra dispatch cost +3 us).
//   - R2 (2 rows/block) neutral; R3 (nontemporal hints) regressed ~+6 us.
// Single fused kernel: one block per row b. Each block
//   1) issues its 4 float4 x-loads (in flight during the count),
//   2) scans the 16 KB assignments array (L2-resident) counting matches to b,
//   3) shuffle+LDS reduces the count, broadcasts,
//   4) scales and stores the row.
// No memset, no atomics, no inter-kernel dependencies: one dispatch total.

#define BLOCK 256
#define C_VEC 1024            // 4096 floats / 4 per float4
#define VPT 4                 // float4 per thread (1024 / 256)
#define APT 4                 // int4 per thread (1024 / 256)

__global__ __launch_bounds__(BLOCK) void mux_fused_kernel(
    const float4* __restrict__ x,
    const int4* __restrict__ a4,
    float4* __restrict__ out) {
    const int b = blockIdx.x;
    const int tid = threadIdx.x;

    // 1) start the row loads early so they overlap the count/reduce
    const long base = (long)b * C_VEC;
    float4 v[VPT];
#pragma unroll
    for (int k = 0; k < VPT; ++k)
        v[k] = x[base + tid + BLOCK * k];

    // 2) per-thread match count over assignments (int4 loads, L2-hit)
    int local = 0;
#pragma unroll
    for (int k = 0; k < APT; ++k) {
        int4 a = a4[tid + BLOCK * k];
        local += (a.x == b) + (a.y == b) + (a.z == b) + (a.w == b);
    }

    // 3) wave shuffle-reduce (width 64) then cross-wave LDS reduce
#pragma unroll
    for (int off = 32; off > 0; off >>= 1)
        local += __shfl_down(local, off, 64);

    __shared__ int wave_sum[BLOCK / 64];
    __shared__ float s_scale;
    const int wave = tid >> 6;
    if ((tid & 63) == 0) wave_sum[wave] = local;
    __syncthreads();
    if (tid == 0)
        s_scale = (float)(wave_sum[0] + wave_sum[1] + wave_sum[2] + wave_sum[3]);
    __syncthreads();
    const float s = s_scale;

    // 4) scale + store
#pragma unroll
    for (int k = 0; k < VPT; ++k) {
        float4 w = v[k];
        w.x *= s; w.y *= s; w.z *= s; w.w *= s;
        out[base + tid + BLOCK * k] = w;
    }
}

extern "C" void kernel_launch(void* const* d_in, const int* in_sizes, int n_in,
                              void* d_out, int out_size, void* d_ws, size_t ws_size,
                              hipStream_t stream) {
    const float* x = (const float*)d_in[0];
    const int* assignments = (const int*)d_in[1];
    float* out = (float*)d_out;

    const int B = 4096;  // rows; one block each
    mux_fused_kernel<<<dim3(B), dim3(BLOCK), 0, stream>>>(
        (const float4*)x, (const int4*)assignments, (float4*)out);
}